// Round 1
// baseline (1219.663 us; speedup 1.0000x reference)
//
#include <hip/hip_runtime.h>
#include <hip/hip_bf16.h>

// ---------------------------------------------------------------------------
// Goal_Conditioned_Policies: conv(3->32,s2) relu, conv(32->64,s2) relu,
// mean-pool, MLP chain with per-sample einsum, softmax.
// B=4096, x[4096,3,64,64] fp32, C[4096,50,50] fp32, out [4096,50] fp32.
//
// k_prep : repack conv2 weights to bf16 [pos=ky*3+kx][oc=64][ic=32]
// k_conv : persistent 256 blocks, 16 samples each, fused conv1+conv2+pool.
//          h1 (32x32x32) lives only in LDS (bf16, phase-split padded layout).
//          conv2 via v_mfma_f32_32x32x16_bf16, weights held in VGPRs.
// k_mlp  : wave-per-sample MLP + einsum + softmax, readlane broadcasts.
// ---------------------------------------------------------------------------

typedef __attribute__((ext_vector_type(8)))  short short8;
typedef __attribute__((ext_vector_type(16))) float floatx16;

#define AS1 __attribute__((address_space(1)))
#define AS3 __attribute__((address_space(3)))

__device__ __forceinline__ unsigned short f2bf(float f) {
    unsigned u = __float_as_uint(f);
    u += 0x7fffu + ((u >> 16) & 1u);   // round-to-nearest-even
    return (unsigned short)(u >> 16);
}

__device__ __forceinline__ float rl(float v, int i) {
    return __int_as_float(__builtin_amdgcn_readlane(__float_as_int(v), i));
}

// ---------------------------------------------------------------------------
// k_prep: conv2_w fp32 [oc][ic][ky][kx] -> packw bf16 [pos][oc][ic]
// ---------------------------------------------------------------------------
__global__ void k_prep(const float* __restrict__ cw2, short* __restrict__ packw) {
    const int idx = blockIdx.x * 256 + threadIdx.x;   // 0..18431
    if (idx < 9 * 64 * 32) {
        const int ic  = idx & 31;
        const int oc  = (idx >> 5) & 63;
        const int pos = idx >> 11;
        packw[idx] = (short)f2bf(cw2[oc * 288 + ic * 9 + pos]);
    }
}

// ---------------------------------------------------------------------------
// k_conv: fused conv1 + conv2 + mean pool.
// LDS layout:
//   xs   : fp32 x sample, global layout [ic][64][64]          49152 B
//   h1   : bf16, rows iy=0..31. row pitch 2592 B = 32 slots*80 + 32 pad.
//          slot(ix) = (ix&1)*16 + (ix>>1)  (phase-split so stride-2 im2col
//          reads are slot-consecutive); slot holds 32 bf16 (+pad to 80 B).
//   pool : 4 waves x 32 partial sums                          512 B
// ---------------------------------------------------------------------------
#define XS_OFF   0
#define H1_OFF   49152
#define ROWB     2592
#define POOL_OFF (49152 + 82944)
#define SMEM_SZ  (49152 + 82944 + 512)
#define SPB      16   // samples per block

__global__ __launch_bounds__(256, 1) void k_conv(
    const float* __restrict__ x,    const float* __restrict__ c1w,
    const float* __restrict__ c1b,  const short* __restrict__ packw,
    const float* __restrict__ c2b,  float* __restrict__ pooled)
{
    __shared__ __align__(16) char smem[SMEM_SZ];
    float* xs      = (float*)(smem + XS_OFF);
    char*  h1b     = smem + H1_OFF;
    float* poolbuf = (float*)(smem + POOL_OFF);

    const int tid  = threadIdx.x;
    const int lane = tid & 63;
    const int w    = tid >> 6;

    // conv2 wave/lane geometry (32x32x16 MFMA):
    //   A-frag: row m = lane&31 -> (ox = m&15, oyb = m>>4), k = (lane>>5)*8+j
    //   B-frag: col n = lane&31 -> oc, same k pattern
    const int nt   = w & 1;          // oc tile (0..1)
    const int mh   = w >> 1;         // m half  (0..1)
    const int ox2  = lane & 15;
    const int oyb  = (lane >> 4) & 1;
    const int ss   = lane >> 5;
    const int ocn  = nt * 32 + (lane & 31);
    const float bias2 = c2b[ocn];

    short8 z8;
    #pragma unroll
    for (int i = 0; i < 8; ++i) z8[i] = 0;

    // B fragments: sample-invariant, load once. bfr[pos][khalf]
    short8 bfr[9][2];
    #pragma unroll
    for (int pos = 0; pos < 9; ++pos) {
        #pragma unroll
        for (int h = 0; h < 2; ++h)
            bfr[pos][h] = *(const short8*)(packw + (pos * 64 + ocn) * 32 + h * 16 + ss * 8);
    }

    // async prefetch of x for sample s into xs (12 KB per wave, 16 B/lane)
    auto prefetch_x = [&](int bb) {
        const char* g = (const char*)(x + (size_t)bb * 12288);
        #pragma unroll
        for (int i = 0; i < 12; ++i) {
            const int off = (w * 12 + i) << 10;   // 1 KB chunks
            __builtin_amdgcn_global_load_lds(
                (const AS1 unsigned int*)(g + off + lane * 16),
                (AS3 unsigned int*)(smem + XS_OFF + off), 16, 0, 0);
        }
    };

    prefetch_x(blockIdx.x);
    __syncthreads();   // drains vmcnt -> xs ready

    for (int s = 0; s < SPB; ++s) {
        const int b = blockIdx.x + (s << 8);

        // ---------------- conv1 (fp32 VALU), 4 pixels/thread ----------------
        #pragma unroll 1
        for (int it = 0; it < 4; ++it) {
            const int p   = tid + (it << 8);
            const int oy1 = p >> 5, ox1 = p & 31;
            float xr[27];
            #pragma unroll
            for (int ic = 0; ic < 3; ++ic) {
                #pragma unroll
                for (int ky = 0; ky < 3; ++ky) {
                    const int iy = oy1 * 2 + ky - 1;
                    #pragma unroll
                    for (int kx = 0; kx < 3; ++kx) {
                        const int ix = ox1 * 2 + kx - 1;
                        const bool ok = (iy >= 0) && (ix >= 0);  // upper bounds never exceeded
                        xr[ic * 9 + ky * 3 + kx] = ok ? xs[ic * 4096 + iy * 64 + ix] : 0.f;
                    }
                }
            }
            const int hb = oy1 * ROWB + ((((ox1 & 1) << 4) + (ox1 >> 1)) * 80);
            #pragma unroll 1
            for (int og = 0; og < 8; ++og) {   // 4 oc at a time: 4 indep FMA chains
                const int o0 = og * 4;
                float a0 = c1b[o0], a1 = c1b[o0 + 1], a2 = c1b[o0 + 2], a3 = c1b[o0 + 3];
                #pragma unroll
                for (int t = 0; t < 27; ++t) {   // weight indices uniform -> s_load
                    const float xv = xr[t];
                    a0 += c1w[(o0    ) * 27 + t] * xv;
                    a1 += c1w[(o0 + 1) * 27 + t] * xv;
                    a2 += c1w[(o0 + 2) * 27 + t] * xv;
                    a3 += c1w[(o0 + 3) * 27 + t] * xv;
                }
                a0 = fmaxf(a0, 0.f); a1 = fmaxf(a1, 0.f);
                a2 = fmaxf(a2, 0.f); a3 = fmaxf(a3, 0.f);
                uint2 v;
                v.x = (unsigned)f2bf(a0) | ((unsigned)f2bf(a1) << 16);
                v.y = (unsigned)f2bf(a2) | ((unsigned)f2bf(a3) << 16);
                *(uint2*)(h1b + hb + og * 8) = v;
            }
        }
        __syncthreads();   // h1 complete; xs fully consumed

        // async prefetch next sample's x (overlaps with conv2)
        if (s + 1 < SPB) prefetch_x(blockIdx.x + ((s + 1) << 8));

        // ---------------- conv2 (MFMA) + bias + relu + pool ----------------
        float pool = 0.f;
        #pragma unroll
        for (int tp = 0; tp < 2; ++tp) {       // 2 mtiles at once (MFMA ILP)
            const int t0 = mh * 4 + tp * 2;    // mtile covers oy {2t,2t+1}
            floatx16 acc0, acc1;
            #pragma unroll
            for (int r = 0; r < 16; ++r) { acc0[r] = 0.f; acc1[r] = 0.f; }
            #pragma unroll
            for (int ky = 0; ky < 3; ++ky) {
                #pragma unroll
                for (int kx = 0; kx < 3; ++kx) {
                    const int iy0 = t0 * 4 + oyb * 2 + ky - 1;
                    const int ph  = (kx + 1) & 1;
                    const int xh  = ox2 - (kx == 0 ? 1 : 0);
                    const bool okx = (xh >= 0);
                    const bool ok0 = okx && (iy0 >= 0);   // t0+1 tile always iy>=3
                    const int sb  = (ph * 16 + xh) * 80 + ss * 16;
                    const int ba0 = iy0 * ROWB + sb;
                    const int ba1 = ba0 + 4 * ROWB;
                    #pragma unroll
                    for (int h = 0; h < 2; ++h) {
                        short8 a0 = ok0 ? *(const short8*)(h1b + ba0 + h * 32) : z8;
                        short8 a1 = okx ? *(const short8*)(h1b + ba1 + h * 32) : z8;
                        const short8 bf = bfr[ky * 3 + kx][h];
                        acc0 = __builtin_amdgcn_mfma_f32_32x32x16_bf16(a0, bf, acc0, 0, 0, 0);
                        acc1 = __builtin_amdgcn_mfma_f32_32x32x16_bf16(a1, bf, acc1, 0, 0, 0);
                    }
                }
            }
            #pragma unroll
            for (int r = 0; r < 16; ++r) {     // bias+relu per pixel, then pool
                pool += fmaxf(acc0[r] + bias2, 0.f);
                pool += fmaxf(acc1[r] + bias2, 0.f);
            }
        }
        pool += __shfl_xor(pool, 32, 64);      // combine k-half lanes (same oc)
        if (lane < 32) poolbuf[w * 32 + lane] = pool;
        __syncthreads();
        if (tid < 64) {
            const int g = tid >> 5, c = tid & 31;
            pooled[(size_t)b * 64 + tid] =
                (poolbuf[g * 32 + c] + poolbuf[(g + 2) * 32 + c]) * (1.f / 256.f);
        }
        __syncthreads();   // poolbuf/h1 reusable; xs(s+1) arrived (vmcnt drain)
    }
}

// ---------------------------------------------------------------------------
// k_mlp: one wave per sample. enc->f1->einsum->f2->concat->f3->f4->f5->out->softmax
// ---------------------------------------------------------------------------
__global__ __launch_bounds__(256, 4) void k_mlp(
    const float* __restrict__ pooled, const float* __restrict__ C,
    const float* __restrict__ ew, const float* __restrict__ eb,
    const float* __restrict__ w1, const float* __restrict__ b1,
    const float* __restrict__ w2, const float* __restrict__ b2,
    const float* __restrict__ w3, const float* __restrict__ b3,
    const float* __restrict__ w4, const float* __restrict__ b4,
    const float* __restrict__ w5, const float* __restrict__ b5,
    const float* __restrict__ ow, const float* __restrict__ ob,
    float* __restrict__ out)
{
    const int lane = threadIdx.x & 63;
    const int w    = threadIdx.x >> 6;
    const int b    = blockIdx.x * 4 + w;
    const int jc   = (lane < 50) ? lane : 0;   // clamp for 50-wide layers

    const float p0 = pooled[(size_t)b * 64 + lane];

    // enc: 64 -> 128, relu. lane holds j and j+64.
    float x1a = eb[lane], x1b = eb[lane + 64];
    #pragma unroll 8
    for (int i = 0; i < 64; ++i) {
        const float ai = rl(p0, i);
        x1a += ai * ew[i * 128 + lane];
        x1b += ai * ew[i * 128 + 64 + lane];
    }
    x1a = fmaxf(x1a, 0.f); x1b = fmaxf(x1b, 0.f);

    // f1: 128 -> 50, relu (lanes >= 50 compute garbage, never consumed)
    float x2 = b1[jc];
    #pragma unroll 8
    for (int i = 0; i < 64; ++i)  x2 += rl(x1a, i) * w1[i * 50 + jc];
    #pragma unroll 8
    for (int i = 0; i < 64; ++i)  x2 += rl(x1b, i) * w1[(64 + i) * 50 + jc];
    x2 = fmaxf(x2, 0.f);

    // einsum: e_i = sum_j C[b][i][j] * x2_j   (no bias, no relu)
    const float* Cb = C + (size_t)b * 2500;
    float e = 0.f;
    #pragma unroll 10
    for (int j = 0; j < 50; ++j) e += Cb[jc * 50 + j] * rl(x2, j);

    // f2: 50 -> 128, relu
    float x3a = b2[lane], x3b = b2[lane + 64];
    #pragma unroll 10
    for (int i = 0; i < 50; ++i) {
        const float ai = rl(e, i);
        x3a += ai * w2[i * 128 + lane];
        x3b += ai * w2[i * 128 + 64 + lane];
    }
    x3a = fmaxf(x3a, 0.f); x3b = fmaxf(x3b, 0.f);

    // f3: concat(x1,x3) 256 -> 64, relu
    float x5 = b3[lane];
    #pragma unroll 8
    for (int i = 0; i < 64; ++i) x5 += rl(x1a, i) * w3[(i      ) * 64 + lane];
    #pragma unroll 8
    for (int i = 0; i < 64; ++i) x5 += rl(x1b, i) * w3[(64  + i) * 64 + lane];
    #pragma unroll 8
    for (int i = 0; i < 64; ++i) x5 += rl(x3a, i) * w3[(128 + i) * 64 + lane];
    #pragma unroll 8
    for (int i = 0; i < 64; ++i) x5 += rl(x3b, i) * w3[(192 + i) * 64 + lane];
    x5 = fmaxf(x5, 0.f);

    // f4, f5: 64 -> 64, relu
    float x6 = b4[lane];
    #pragma unroll 8
    for (int i = 0; i < 64; ++i) x6 += rl(x5, i) * w4[i * 64 + lane];
    x6 = fmaxf(x6, 0.f);
    float x7 = b5[lane];
    #pragma unroll 8
    for (int i = 0; i < 64; ++i) x7 += rl(x6, i) * w5[i * 64 + lane];
    x7 = fmaxf(x7, 0.f);

    // out: 64 -> 50, relu, softmax
    float lg = ob[jc];
    #pragma unroll 8
    for (int i = 0; i < 64; ++i) lg += rl(x7, i) * ow[i * 50 + jc];
    float z = (lane < 50) ? fmaxf(lg, 0.f) : -1e30f;

    float m = z;
    #pragma unroll
    for (int o = 32; o > 0; o >>= 1) m = fmaxf(m, __shfl_xor(m, o, 64));
    float pr = __expf(z - m);
    float sden = pr;
    #pragma unroll
    for (int o = 32; o > 0; o >>= 1) sden += __shfl_xor(sden, o, 64);

    if (lane < 50) out[(size_t)b * 50 + lane] = pr / sden;
}

// ---------------------------------------------------------------------------
extern "C" void kernel_launch(void* const* d_in, const int* in_sizes, int n_in,
                              void* d_out, int out_size, void* d_ws, size_t ws_size,
                              hipStream_t stream) {
    (void)in_sizes; (void)n_in; (void)out_size; (void)ws_size;
    const float* x   = (const float*)d_in[0];
    const float* Cm  = (const float*)d_in[1];
    const float* c1w = (const float*)d_in[2];
    const float* c1b = (const float*)d_in[3];
    const float* c2w = (const float*)d_in[4];
    const float* c2b = (const float*)d_in[5];
    const float* ew  = (const float*)d_in[6];
    const float* ebv = (const float*)d_in[7];
    const float* f1w = (const float*)d_in[8];
    const float* f1b = (const float*)d_in[9];
    const float* f2w = (const float*)d_in[10];
    const float* f2b = (const float*)d_in[11];
    const float* f3w = (const float*)d_in[12];
    const float* f3b = (const float*)d_in[13];
    const float* f4w = (const float*)d_in[14];
    const float* f4b = (const float*)d_in[15];
    const float* f5w = (const float*)d_in[16];
    const float* f5b = (const float*)d_in[17];
    const float* ow  = (const float*)d_in[18];
    const float* ob  = (const float*)d_in[19];

    short* packw  = (short*)d_ws;                      // 36864 B
    float* pooled = (float*)((char*)d_ws + 65536);     // 4096*64*4 B
    float* out    = (float*)d_out;

    hipLaunchKernelGGL(k_prep, dim3(72),   dim3(256), 0, stream, c2w, packw);
    hipLaunchKernelGGL(k_conv, dim3(256),  dim3(256), 0, stream, x, c1w, c1b, packw, c2b, pooled);
    hipLaunchKernelGGL(k_mlp,  dim3(1024), dim3(256), 0, stream, pooled, Cm,
                       ew, ebv, f1w, f1b, f2w, f2b, f3w, f3b, f4w, f4b, f5w, f5b,
                       ow, ob, out);
}

// Round 2
// 430.736 us; speedup vs baseline: 2.8316x; 2.8316x over previous
//
#include <hip/hip_runtime.h>
#include <hip/hip_bf16.h>

// ---------------------------------------------------------------------------
// Goal_Conditioned_Policies: conv(3->32,s2) relu, conv(32->64,s2) relu,
// mean-pool, MLP chain with per-sample einsum, softmax.
// B=4096, x[4096,3,64,64] fp32, C[4096,50,50] fp32, out [4096,50] fp32.
//
// Round 2: conv1 moved to MFMA (implicit GEMM, im2col in LDS).
//   k_prep : pack conv2 w -> bf16 [pos][oc][ic=32] and conv1 w -> [oc][k=32pad]
//   k_conv : 256 persistent blocks x 16 samples. Per sample:
//            xs (fp32, 48KB, async global_load_lds, prefetch s+1 in flight
//            across lgkm-only barriers) -> im2col A1 (bf16, K=27 pad 32,
//            512px halves, 80B stride) -> conv1 MFMA 32x32x16 -> h1 LDS
//            (bf16, phase-split 64B slots, row pitch 2064 = conflict-free)
//            -> conv2 MFMA (B-frags in VGPRs) -> bias/relu/mean-pool.
//   k_mlp  : wave-per-sample MLP + einsum (float2 C reads) + softmax.
// ---------------------------------------------------------------------------

typedef __attribute__((ext_vector_type(8)))  short short8;
typedef __attribute__((ext_vector_type(16))) float floatx16;

#define AS1 __attribute__((address_space(1)))
#define AS3 __attribute__((address_space(3)))

// barriers: lgkm-only keeps async global_load_lds (vmcnt) in flight
#define BAR_LGKM() asm volatile("s_waitcnt lgkmcnt(0)\ns_barrier" ::: "memory")
#define BAR_FULL() asm volatile("s_waitcnt vmcnt(0) lgkmcnt(0)\ns_barrier" ::: "memory")

__device__ __forceinline__ short f2bf(float f) {
    unsigned u = __float_as_uint(f);
    u += 0x7fffu + ((u >> 16) & 1u);   // round-to-nearest-even
    return (short)(u >> 16);
}

__device__ __forceinline__ float rl(float v, int i) {
    return __int_as_float(__builtin_amdgcn_readlane(__float_as_int(v), i));
}

__device__ __forceinline__ unsigned pkbf2(float a, float b) {
    float2 fp; fp.x = a; fp.y = b;
    __hip_bfloat162 bb = __float22bfloat162_rn(fp);
    return *(unsigned*)&bb;
}

// ---------------------------------------------------------------------------
// k_prep: packw[0..18431]  = conv2 bf16 [pos=ky*3+kx][oc=64][ic=32]
//         packw[18432..]   = conv1 bf16 [oc=32][k=32] (k=ic*9+ky*3+kx, pad 0)
// ---------------------------------------------------------------------------
__global__ void k_prep(const float* __restrict__ cw2, const float* __restrict__ cw1,
                       short* __restrict__ packw) {
    const int idx = blockIdx.x * 256 + threadIdx.x;
    if (idx < 9 * 64 * 32) {
        const int ic  = idx & 31;
        const int oc  = (idx >> 5) & 63;
        const int pos = idx >> 11;
        packw[idx] = f2bf(cw2[oc * 288 + ic * 9 + pos]);
    } else if (idx < 9 * 64 * 32 + 32 * 32) {
        const int j  = idx - 9 * 64 * 32;
        const int k  = j & 31;
        const int oc = j >> 5;
        packw[idx] = (k < 27) ? f2bf(cw1[oc * 27 + k]) : (short)0;
    }
}

// ---------------------------------------------------------------------------
// k_conv LDS layout
//   xs : fp32 x sample [ic][64][64]                    49152 B
//   A1 : im2col half, 512 px * 80 B (32 bf16 + pad)    40960 B  (pool overlay)
//   h1 : bf16 [iy=32][slot=32][oc=32], row pitch 2064  66048 B
// ---------------------------------------------------------------------------
#define XS_OFF  0
#define A1_OFF  49152
#define A1STR   80
#define H1_OFF  90112
#define ROWB    2064
#define SMEM_SZ (49152 + 40960 + 66048)
#define SPB     16

__global__ __launch_bounds__(256, 1) void k_conv(
    const float* __restrict__ x,    const float* __restrict__ c1b,
    const short* __restrict__ packw, const float* __restrict__ c2b,
    float* __restrict__ pooled)
{
    __shared__ __align__(16) char smem[SMEM_SZ];
    float* xs      = (float*)(smem + XS_OFF);
    char*  a1      = smem + A1_OFF;
    char*  h1b     = smem + H1_OFF;
    float* poolbuf = (float*)(smem + A1_OFF);   // overlays A1 (dead during pool)

    const int tid  = threadIdx.x;
    const int lane = tid & 63;
    const int w    = tid >> 6;

    const int col = lane & 31;   // MFMA col (oc for conv1, n for conv2)
    const int ss  = lane >> 5;   // k-subgroup within 16-chunk

    // conv2 wave/lane geometry (as round 1, verified)
    const int nt  = w & 1;
    const int mh  = w >> 1;
    const int ox2 = lane & 15;
    const int oyb = (lane >> 4) & 1;
    const int ocn = nt * 32 + col;
    const float bias2 = c2b[ocn];
    const float bias1 = c1b[col];

    short8 z8;
    #pragma unroll
    for (int i = 0; i < 8; ++i) z8[i] = 0;

    // conv2 B fragments (sample-invariant): bfr[pos][kchunk]
    short8 bfr[9][2];
    #pragma unroll
    for (int pos = 0; pos < 9; ++pos)
        #pragma unroll
        for (int h = 0; h < 2; ++h)
            bfr[pos][h] = *(const short8*)(packw + (pos * 64 + ocn) * 32 + h * 16 + ss * 8);

    // conv1 B fragments: W1p[oc][k], lane col=oc, k = kstep*16 + ss*8 + j
    const short* w1p = packw + 18432;
    short8 w1f[2];
    #pragma unroll
    for (int k = 0; k < 2; ++k)
        w1f[k] = *(const short8*)(w1p + col * 32 + k * 16 + ss * 8);

    // async prefetch of x for one sample into xs (12 KB per wave, 16 B/lane)
    auto prefetch_x = [&](int bb) {
        const char* g = (const char*)(x + (size_t)bb * 12288);
        #pragma unroll
        for (int i = 0; i < 12; ++i) {
            const int off = (w * 12 + i) << 10;   // 1 KB chunks
            __builtin_amdgcn_global_load_lds(
                (const AS1 unsigned int*)(g + off + lane * 16),
                (AS3 unsigned int*)(smem + XS_OFF + off), 16, 0, 0);
        }
    };

    // ---- im2col for one 512-pixel half: A1[p][k] bf16, k=ic*9+ky*3+kx ----
    auto im2col = [&](int half) {
        #pragma unroll
        for (int px = 0; px < 2; ++px) {
            const int p  = tid + px * 256;
            const int oy = half * 16 + (p >> 5);
            const int ox = p & 31;
            float f[32];
            #pragma unroll
            for (int ic = 0; ic < 3; ++ic) {
                #pragma unroll
                for (int ky = 0; ky < 3; ++ky) {
                    const int  iy   = 2 * oy + ky - 1;
                    const bool oky  = iy >= 0;           // iy<=63 always
                    const int  base = ic * 4096 + (oky ? iy : 0) * 64 + 2 * ox;
                    const float2 p12 = *(const float2*)(xs + base);   // ix=2ox,2ox+1
                    const float  v0  = xs[(base > 0) ? base - 1 : 0]; // ix=2ox-1
                    const int k = ic * 9 + ky * 3;
                    f[k + 0] = (oky && ox > 0) ? v0 : 0.f;
                    f[k + 1] = oky ? p12.x : 0.f;
                    f[k + 2] = oky ? p12.y : 0.f;
                }
            }
            f[27] = 0.f; f[28] = 0.f; f[29] = 0.f; f[30] = 0.f; f[31] = 0.f;
            unsigned pk[16];
            #pragma unroll
            for (int t = 0; t < 16; ++t) pk[t] = pkbf2(f[2 * t], f[2 * t + 1]);
            uint4* dst = (uint4*)(a1 + p * A1STR);
            dst[0] = make_uint4(pk[0],  pk[1],  pk[2],  pk[3]);
            dst[1] = make_uint4(pk[4],  pk[5],  pk[6],  pk[7]);
            dst[2] = make_uint4(pk[8],  pk[9],  pk[10], pk[11]);
            dst[3] = make_uint4(pk[12], pk[13], pk[14], pk[15]);
        }
    };

    // ---- conv1 MFMA on one half: 4 m-tiles/wave, write h1 rows ----
    auto conv1_mfma = [&](int half) {
        #pragma unroll
        for (int i = 0; i < 4; ++i) {
            const int t = w * 4 + i;                       // output row within half
            const char* abase = a1 + (t * 32 + col) * A1STR + ss * 16;
            const short8 af0 = *(const short8*)(abase);
            const short8 af1 = *(const short8*)(abase + 32);
            floatx16 acc;
            #pragma unroll
            for (int r = 0; r < 16; ++r) acc[r] = 0.f;
            acc = __builtin_amdgcn_mfma_f32_32x32x16_bf16(af0, w1f[0], acc, 0, 0, 0);
            acc = __builtin_amdgcn_mfma_f32_32x32x16_bf16(af1, w1f[1], acc, 0, 0, 0);
            const int oyg = half * 16 + t;
            char* hb = h1b + oyg * ROWB + col * 2;
            #pragma unroll
            for (int r = 0; r < 16; r += 2) {
                const int row = (r & 3) + 8 * (r >> 2) + 4 * ss;   // even; pair row,row+1
                const unsigned u = pkbf2(fmaxf(acc[r]     + bias1, 0.f),
                                         fmaxf(acc[r + 1] + bias1, 0.f));
                *(unsigned short*)(hb + (row >> 1) * 64)        = (unsigned short)u;
                *(unsigned short*)(hb + (row >> 1) * 64 + 1024) = (unsigned short)(u >> 16);
            }
        }
    };

    prefetch_x(blockIdx.x);

    #pragma unroll 1
    for (int s = 0; s < SPB; ++s) {
        const int b = blockIdx.x + (s << 8);

        BAR_FULL();          // xs(s) arrived; all LDS phases of s-1 settled
        im2col(0);
        BAR_LGKM();          // A1 half-0 ready
        conv1_mfma(0);
        BAR_LGKM();          // A1 reads done -> reusable
        im2col(1);
        BAR_LGKM();          // A1 half-1 ready; xs fully consumed
        if (s + 1 < SPB) prefetch_x(blockIdx.x + ((s + 1) << 8));   // stays in flight
        conv1_mfma(1);
        BAR_LGKM();          // h1 complete & visible

        // ---------------- conv2 (MFMA) + bias + relu + pool ----------------
        float pool = 0.f;
        #pragma unroll
        for (int tp = 0; tp < 2; ++tp) {
            const int t0 = mh * 4 + tp * 2;
            floatx16 acc0, acc1;
            #pragma unroll
            for (int r = 0; r < 16; ++r) { acc0[r] = 0.f; acc1[r] = 0.f; }
            #pragma unroll
            for (int ky = 0; ky < 3; ++ky) {
                #pragma unroll
                for (int kx = 0; kx < 3; ++kx) {
                    const int  iy0 = t0 * 4 + oyb * 2 + ky - 1;
                    const int  ph  = (kx + 1) & 1;
                    const int  xh  = ox2 - (kx == 0 ? 1 : 0);
                    const bool okx = (xh >= 0);
                    const bool ok0 = okx && (iy0 >= 0);
                    const int  sb  = (ph * 16 + xh) * 64 + ss * 16;
                    const int  ba0 = iy0 * ROWB + sb;
                    const int  ba1 = ba0 + 4 * ROWB;
                    #pragma unroll
                    for (int h = 0; h < 2; ++h) {
                        short8 a0v = ok0 ? *(const short8*)(h1b + ba0 + h * 32) : z8;
                        short8 a1v = okx ? *(const short8*)(h1b + ba1 + h * 32) : z8;
                        const short8 bf = bfr[ky * 3 + kx][h];
                        acc0 = __builtin_amdgcn_mfma_f32_32x32x16_bf16(a0v, bf, acc0, 0, 0, 0);
                        acc1 = __builtin_amdgcn_mfma_f32_32x32x16_bf16(a1v, bf, acc1, 0, 0, 0);
                    }
                }
            }
            #pragma unroll
            for (int r = 0; r < 16; ++r) {
                pool += fmaxf(acc0[r] + bias2, 0.f);
                pool += fmaxf(acc1[r] + bias2, 0.f);
            }
        }
        pool += __shfl_xor(pool, 32, 64);      // combine k-half lanes (same oc)
        if (lane < 32) poolbuf[w * 32 + lane] = pool;
        BAR_LGKM();          // poolbuf visible
        if (tid < 64) {
            const int g = tid >> 5, c = tid & 31;
            pooled[(size_t)b * 64 + tid] =
                (poolbuf[g * 32 + c] + poolbuf[(g + 2) * 32 + c]) * (1.f / 256.f);
        }
        // loop-top BAR_FULL separates poolbuf reads from next im2col writes
    }
}

// ---------------------------------------------------------------------------
// k_mlp: one wave per sample. enc->f1->einsum->f2->concat->f3->f4->f5->out->softmax
// ---------------------------------------------------------------------------
__global__ __launch_bounds__(256, 4) void k_mlp(
    const float* __restrict__ pooled, const float* __restrict__ C,
    const float* __restrict__ ew, const float* __restrict__ eb,
    const float* __restrict__ w1, const float* __restrict__ b1,
    const float* __restrict__ w2, const float* __restrict__ b2,
    const float* __restrict__ w3, const float* __restrict__ b3,
    const float* __restrict__ w4, const float* __restrict__ b4,
    const float* __restrict__ w5, const float* __restrict__ b5,
    const float* __restrict__ ow, const float* __restrict__ ob,
    float* __restrict__ out)
{
    const int lane = threadIdx.x & 63;
    const int w    = threadIdx.x >> 6;
    const int b    = blockIdx.x * 4 + w;
    const int jc   = (lane < 50) ? lane : 0;   // clamp for 50-wide layers

    const float p0 = pooled[(size_t)b * 64 + lane];

    // enc: 64 -> 128, relu. lane holds j and j+64.
    float x1a = eb[lane], x1b = eb[lane + 64];
    #pragma unroll 8
    for (int i = 0; i < 64; ++i) {
        const float ai = rl(p0, i);
        x1a += ai * ew[i * 128 + lane];
        x1b += ai * ew[i * 128 + 64 + lane];
    }
    x1a = fmaxf(x1a, 0.f); x1b = fmaxf(x1b, 0.f);

    // f1: 128 -> 50, relu (lanes >= 50 compute garbage, never consumed)
    float x2 = b1[jc];
    #pragma unroll 8
    for (int i = 0; i < 64; ++i)  x2 += rl(x1a, i) * w1[i * 50 + jc];
    #pragma unroll 8
    for (int i = 0; i < 64; ++i)  x2 += rl(x1b, i) * w1[(64 + i) * 50 + jc];
    x2 = fmaxf(x2, 0.f);

    // einsum: e_i = sum_j C[b][i][j] * x2_j   (float2 reads: 25 instrs/lane)
    const float2* C2 = (const float2*)(C + (size_t)b * 2500 + jc * 50);
    float e = 0.f;
    #pragma unroll 5
    for (int j = 0; j < 25; ++j) {
        const float2 cc = C2[j];
        e += cc.x * rl(x2, 2 * j) + cc.y * rl(x2, 2 * j + 1);
    }

    // f2: 50 -> 128, relu
    float x3a = b2[lane], x3b = b2[lane + 64];
    #pragma unroll 10
    for (int i = 0; i < 50; ++i) {
        const float ai = rl(e, i);
        x3a += ai * w2[i * 128 + lane];
        x3b += ai * w2[i * 128 + 64 + lane];
    }
    x3a = fmaxf(x3a, 0.f); x3b = fmaxf(x3b, 0.f);

    // f3: concat(x1,x3) 256 -> 64, relu
    float x5 = b3[lane];
    #pragma unroll 8
    for (int i = 0; i < 64; ++i) x5 += rl(x1a, i) * w3[(i      ) * 64 + lane];
    #pragma unroll 8
    for (int i = 0; i < 64; ++i) x5 += rl(x1b, i) * w3[(64  + i) * 64 + lane];
    #pragma unroll 8
    for (int i = 0; i < 64; ++i) x5 += rl(x3a, i) * w3[(128 + i) * 64 + lane];
    #pragma unroll 8
    for (int i = 0; i < 64; ++i) x5 += rl(x3b, i) * w3[(192 + i) * 64 + lane];
    x5 = fmaxf(x5, 0.f);

    // f4, f5: 64 -> 64, relu
    float x6 = b4[lane];
    #pragma unroll 8
    for (int i = 0; i < 64; ++i) x6 += rl(x5, i) * w4[i * 64 + lane];
    x6 = fmaxf(x6, 0.f);
    float x7 = b5[lane];
    #pragma unroll 8
    for (int i = 0; i < 64; ++i) x7 += rl(x6, i) * w5[i * 64 + lane];
    x7 = fmaxf(x7, 0.f);

    // out: 64 -> 50, relu, softmax
    float lg = ob[jc];
    #pragma unroll 8
    for (int i = 0; i < 64; ++i) lg += rl(x7, i) * ow[i * 50 + jc];
    float z = (lane < 50) ? fmaxf(lg, 0.f) : -1e30f;

    float m = z;
    #pragma unroll
    for (int o = 32; o > 0; o >>= 1) m = fmaxf(m, __shfl_xor(m, o, 64));
    float pr = __expf(z - m);
    float sden = pr;
    #pragma unroll
    for (int o = 32; o > 0; o >>= 1) sden += __shfl_xor(sden, o, 64);

    if (lane < 50) out[(size_t)b * 50 + lane] = pr / sden;
}

// ---------------------------------------------------------------------------
extern "C" void kernel_launch(void* const* d_in, const int* in_sizes, int n_in,
                              void* d_out, int out_size, void* d_ws, size_t ws_size,
                              hipStream_t stream) {
    (void)in_sizes; (void)n_in; (void)out_size; (void)ws_size;
    const float* x   = (const float*)d_in[0];
    const float* Cm  = (const float*)d_in[1];
    const float* c1w = (const float*)d_in[2];
    const float* c1b = (const float*)d_in[3];
    const float* c2w = (const float*)d_in[4];
    const float* c2b = (const float*)d_in[5];
    const float* ew  = (const float*)d_in[6];
    const float* ebv = (const float*)d_in[7];
    const float* f1w = (const float*)d_in[8];
    const float* f1b = (const float*)d_in[9];
    const float* f2w = (const float*)d_in[10];
    const float* f2b = (const float*)d_in[11];
    const float* f3w = (const float*)d_in[12];
    const float* f3b = (const float*)d_in[13];
    const float* f4w = (const float*)d_in[14];
    const float* f4b = (const float*)d_in[15];
    const float* f5w = (const float*)d_in[16];
    const float* f5b = (const float*)d_in[17];
    const float* ow  = (const float*)d_in[18];
    const float* ob  = (const float*)d_in[19];

    short* packw  = (short*)d_ws;                      // 19456 shorts
    float* pooled = (float*)((char*)d_ws + 65536);     // 4096*64*4 B
    float* out    = (float*)d_out;

    hipLaunchKernelGGL(k_prep, dim3(76),   dim3(256), 0, stream, c2w, c1w, packw);
    hipLaunchKernelGGL(k_conv, dim3(256),  dim3(256), 0, stream, x, c1b, packw, c2b, pooled);
    hipLaunchKernelGGL(k_mlp,  dim3(1024), dim3(256), 0, stream, pooled, Cm,
                       ew, ebv, f1w, f1b, f2w, f2b, f3w, f3b, f4w, f4b, f5w, f5b,
                       ow, ob, out);
}

// Round 3
// 396.648 us; speedup vs baseline: 3.0749x; 1.0859x over previous
//
#include <hip/hip_runtime.h>
#include <hip/hip_bf16.h>

// ---------------------------------------------------------------------------
// Goal_Conditioned_Policies: conv(3->32,s2) relu, conv(32->64,s2) relu,
// mean-pool, MLP chain with per-sample einsum, softmax.
// B=4096, x[4096,3,64,64] fp32, C[4096,50,50] fp32, out [4096,50] fp32.
//
// Round 3: 512-thread k_conv (8 waves, 2/SIMD), h1 XOR chunk-swizzle
// (conflict-free conv2 A-reads), conv1 operands swapped (A=weights) so
// h1 writes are b32 not b16. LDS unchanged at 156160 B (1 block/CU).
// ---------------------------------------------------------------------------

typedef __attribute__((ext_vector_type(8)))  short short8;
typedef __attribute__((ext_vector_type(16))) float floatx16;

#define AS1 __attribute__((address_space(1)))
#define AS3 __attribute__((address_space(3)))

// barriers: lgkm-only keeps async global_load_lds (vmcnt) in flight
#define BAR_LGKM() asm volatile("s_waitcnt lgkmcnt(0)\ns_barrier" ::: "memory")
#define BAR_FULL() asm volatile("s_waitcnt vmcnt(0) lgkmcnt(0)\ns_barrier" ::: "memory")

__device__ __forceinline__ short f2bf(float f) {
    unsigned u = __float_as_uint(f);
    u += 0x7fffu + ((u >> 16) & 1u);   // round-to-nearest-even
    return (short)(u >> 16);
}

__device__ __forceinline__ float rl(float v, int i) {
    return __int_as_float(__builtin_amdgcn_readlane(__float_as_int(v), i));
}

__device__ __forceinline__ unsigned pkbf2(float a, float b) {
    float2 fp; fp.x = a; fp.y = b;
    __hip_bfloat162 bb = __float22bfloat162_rn(fp);
    return *(unsigned*)&bb;
}

// ---------------------------------------------------------------------------
// k_prep: packw[0..18431]  = conv2 bf16 [pos=ky*3+kx][oc=64][ic=32]
//         packw[18432..]   = conv1 bf16 [oc=32][k=32] (k=ic*9+ky*3+kx, pad 0)
// ---------------------------------------------------------------------------
__global__ void k_prep(const float* __restrict__ cw2, const float* __restrict__ cw1,
                       short* __restrict__ packw) {
    const int idx = blockIdx.x * 256 + threadIdx.x;
    if (idx < 9 * 64 * 32) {
        const int ic  = idx & 31;
        const int oc  = (idx >> 5) & 63;
        const int pos = idx >> 11;
        packw[idx] = f2bf(cw2[oc * 288 + ic * 9 + pos]);
    } else if (idx < 9 * 64 * 32 + 32 * 32) {
        const int j  = idx - 9 * 64 * 32;
        const int k  = j & 31;
        const int oc = j >> 5;
        packw[idx] = (k < 27) ? f2bf(cw1[oc * 27 + k]) : (short)0;
    }
}

// ---------------------------------------------------------------------------
// k_conv LDS layout
//   xs : fp32 x sample [ic][64][64]                     49152 B
//   A1 : im2col half, 512 px * 80 B (32 bf16 + pad)     40960 B  (pool overlay)
//   h1 : bf16 [iy=32][slot=32][oc=32], row pitch 2064.
//        slot(ox) = (ox&1)*16 + (ox>>1); within a 64 B slot the four 16 B
//        oc-chunks are stored at chunk' = chunk ^ ((slot>>1)&3)  (bank swizzle)
// ---------------------------------------------------------------------------
#define XS_OFF  0
#define A1_OFF  49152
#define A1STR   80
#define H1_OFF  90112
#define ROWB    2064
#define SMEM_SZ (49152 + 40960 + 66048)
#define SPB     16

__global__ __launch_bounds__(512, 2) void k_conv(
    const float* __restrict__ x,    const float* __restrict__ c1b,
    const short* __restrict__ packw, const float* __restrict__ c2b,
    float* __restrict__ pooled)
{
    __shared__ __align__(16) char smem[SMEM_SZ];
    float* xs      = (float*)(smem + XS_OFF);
    char*  a1      = smem + A1_OFF;
    char*  h1b     = smem + H1_OFF;
    float* poolbuf = (float*)(smem + A1_OFF);   // overlays A1 (dead during pool)

    const int tid  = threadIdx.x;
    const int lane = tid & 63;
    const int w    = tid >> 6;           // 0..7

    const int col = lane & 31;           // MFMA lane col
    const int ss  = lane >> 5;           // k-subgroup

    // conv2 geometry: nt = oc half, each wave does m-tiles t0 = (w>>1) + 4*tp
    const int nt  = w & 1;
    const int ox2 = lane & 15;
    const int oyb = (lane >> 4) & 1;
    const int ocn = nt * 32 + col;
    const float bias2 = c2b[ocn];

    short8 z8;
    #pragma unroll
    for (int i = 0; i < 8; ++i) z8[i] = 0;

    // conv2 B fragments (sample-invariant): bfr[pos][kchunk]
    short8 bfr[9][2];
    #pragma unroll
    for (int pos = 0; pos < 9; ++pos)
        #pragma unroll
        for (int h = 0; h < 2; ++h)
            bfr[pos][h] = *(const short8*)(packw + (pos * 64 + ocn) * 32 + h * 16 + ss * 8);

    // conv1 A fragments (weights): lane m=oc=col, k = ss*8 + j (+16 per chunk)
    const short* w1p = packw + 18432;
    short8 w1f[2];
    #pragma unroll
    for (int k = 0; k < 2; ++k)
        w1f[k] = *(const short8*)(w1p + col * 32 + k * 16 + ss * 8);

    // conv1 bias pairs: D rows = oc = 2*(rp&1) + 8*(rp>>1) + 4*ss (pairs rp)
    float2 b1p[8];
    #pragma unroll
    for (int rp = 0; rp < 8; ++rp)
        b1p[rp] = *(const float2*)(c1b + ((rp & 1) * 2 + (rp >> 1) * 8 + 4 * ss));

    // conv2 A-read swizzled slot offsets (sample-invariant per lane):
    //   slot = ph*16 + xh, phys = slot*64 + ((ss+2h) ^ ((slot>>1)&3))*16
    int  sbv[3][2];
    bool okx[3];
    #pragma unroll
    for (int kx = 0; kx < 3; ++kx) {
        const int ph   = (kx + 1) & 1;
        const int xh   = ox2 - (kx == 0 ? 1 : 0);
        const int slot = ph * 16 + xh;
        const int swz  = (slot >> 1) & 3;
        okx[kx] = (xh >= 0);
        #pragma unroll
        for (int h = 0; h < 2; ++h)
            sbv[kx][h] = slot * 64 + (((ss + 2 * h) ^ swz) << 4);
    }

    // conv1 h1-write base (lane-invariant part): col here is the pixel ox
    const int slotpx = ((col & 1) << 4) + (col >> 1);
    const int wswz   = (slotpx >> 1) & 3;
    const int wbase  = slotpx * 64 + ss * 8;

    // async prefetch of x for one sample into xs (6 KB per wave, 16 B/lane)
    auto prefetch_x = [&](int bb) {
        const char* g = (const char*)(x + (size_t)bb * 12288);
        #pragma unroll
        for (int i = 0; i < 6; ++i) {
            const int off = (w * 6 + i) << 10;   // 1 KB chunks
            __builtin_amdgcn_global_load_lds(
                (const AS1 unsigned int*)(g + off + lane * 16),
                (AS3 unsigned int*)(smem + XS_OFF + off), 16, 0, 0);
        }
    };

    // ---- im2col for one 512-pixel half: A1[p][k] bf16, k=ic*9+ky*3+kx ----
    auto im2col = [&](int half) {
        const int p  = tid;               // pixel index within half
        const int oy = half * 16 + (p >> 5);
        const int ox = p & 31;
        float f[32];
        #pragma unroll
        for (int ic = 0; ic < 3; ++ic) {
            #pragma unroll
            for (int ky = 0; ky < 3; ++ky) {
                const int  iy   = 2 * oy + ky - 1;
                const bool oky  = iy >= 0;           // iy<=63 always
                const int  base = ic * 4096 + (oky ? iy : 0) * 64 + 2 * ox;
                const float2 p12 = *(const float2*)(xs + base);             // ix=2ox,2ox+1
                const float2 pm  = *(const float2*)(xs + (base >= 2 ? base - 2 : 0));
                const int k = ic * 9 + ky * 3;
                f[k + 0] = (oky && ox > 0) ? pm.y : 0.f;                    // ix=2ox-1
                f[k + 1] = oky ? p12.x : 0.f;
                f[k + 2] = oky ? p12.y : 0.f;
            }
        }
        f[27] = 0.f; f[28] = 0.f; f[29] = 0.f; f[30] = 0.f; f[31] = 0.f;
        unsigned pk[16];
        #pragma unroll
        for (int t = 0; t < 16; ++t) pk[t] = pkbf2(f[2 * t], f[2 * t + 1]);
        uint4* dst = (uint4*)(a1 + p * A1STR);
        dst[0] = make_uint4(pk[0],  pk[1],  pk[2],  pk[3]);
        dst[1] = make_uint4(pk[4],  pk[5],  pk[6],  pk[7]);
        dst[2] = make_uint4(pk[8],  pk[9],  pk[10], pk[11]);
        dst[3] = make_uint4(pk[12], pk[13], pk[14], pk[15]);
    };

    // ---- conv1 MFMA on one half: A=weights(m=oc), B=pixels(n=px) ----
    auto conv1_mfma = [&](int half) {
        #pragma unroll
        for (int i = 0; i < 2; ++i) {
            const int t = w * 2 + i;                       // tile = image row in half
            const char* abase = a1 + (t * 32 + col) * A1STR + ss * 16;
            const short8 bf0 = *(const short8*)(abase);
            const short8 bf1 = *(const short8*)(abase + 32);
            floatx16 acc;
            #pragma unroll
            for (int r = 0; r < 16; ++r) acc[r] = 0.f;
            acc = __builtin_amdgcn_mfma_f32_32x32x16_bf16(w1f[0], bf0, acc, 0, 0, 0);
            acc = __builtin_amdgcn_mfma_f32_32x32x16_bf16(w1f[1], bf1, acc, 0, 0, 0);
            const int oyg = half * 16 + t;
            char* hb = h1b + oyg * ROWB + wbase;
            #pragma unroll
            for (int rp = 0; rp < 8; ++rp) {               // pairs: oc0, oc0+1
                const unsigned u = pkbf2(fmaxf(acc[2 * rp]     + b1p[rp].x, 0.f),
                                         fmaxf(acc[2 * rp + 1] + b1p[rp].y, 0.f));
                const int off = (((rp >> 1) ^ wswz) << 4) + (rp & 1) * 4;
                *(unsigned*)(hb + off) = u;
            }
        }
    };

    prefetch_x(blockIdx.x);

    #pragma unroll 1
    for (int s = 0; s < SPB; ++s) {
        const int b = blockIdx.x + (s << 8);

        BAR_FULL();          // xs(s) arrived; all LDS phases of s-1 settled
        im2col(0);
        BAR_LGKM();          // A1 half-0 ready
        conv1_mfma(0);
        BAR_LGKM();          // A1 reads done -> reusable
        im2col(1);
        BAR_LGKM();          // A1 half-1 ready; xs fully consumed
        if (s + 1 < SPB) prefetch_x(blockIdx.x + ((s + 1) << 8));   // stays in flight
        conv1_mfma(1);
        BAR_LGKM();          // h1 complete & visible

        // ---------------- conv2 (MFMA) + bias + relu + pool ----------------
        // two m-tiles (t0, t0+4) interleaved for MFMA ILP
        const int t0 = w >> 1;
        float pool = 0.f;
        floatx16 acc0, acc1;
        #pragma unroll
        for (int r = 0; r < 16; ++r) { acc0[r] = 0.f; acc1[r] = 0.f; }
        #pragma unroll
        for (int ky = 0; ky < 3; ++ky) {
            #pragma unroll
            for (int kx = 0; kx < 3; ++kx) {
                const int  iy0 = t0 * 4 + oyb * 2 + ky - 1;   // tile t0 (may be -1)
                const bool ok0 = okx[kx] && (iy0 >= 0);
                const bool ok1 = okx[kx];                     // tile t0+4: iy>=15
                const int  ba0 = iy0 * ROWB;
                const int  ba1 = ba0 + 16 * ROWB;
                #pragma unroll
                for (int h = 0; h < 2; ++h) {
                    const int so = sbv[kx][h];
                    short8 a0v = ok0 ? *(const short8*)(h1b + ba0 + so) : z8;
                    short8 a1v = ok1 ? *(const short8*)(h1b + ba1 + so) : z8;
                    const short8 bf = bfr[ky * 3 + kx][h];
                    acc0 = __builtin_amdgcn_mfma_f32_32x32x16_bf16(a0v, bf, acc0, 0, 0, 0);
                    acc1 = __builtin_amdgcn_mfma_f32_32x32x16_bf16(a1v, bf, acc1, 0, 0, 0);
                }
            }
        }
        #pragma unroll
        for (int r = 0; r < 16; ++r) {
            pool += fmaxf(acc0[r] + bias2, 0.f);
            pool += fmaxf(acc1[r] + bias2, 0.f);
        }
        pool += __shfl_xor(pool, 32, 64);      // combine k-half lanes (same oc)
        if (lane < 32) poolbuf[w * 32 + lane] = pool;
        BAR_LGKM();          // poolbuf visible
        if (tid < 64) {
            const int g = tid >> 5, c = tid & 31;   // g = oc half = nt
            pooled[(size_t)b * 64 + tid] =
                (poolbuf[(g    ) * 32 + c] + poolbuf[(g + 2) * 32 + c] +
                 poolbuf[(g + 4) * 32 + c] + poolbuf[(g + 6) * 32 + c]) * (1.f / 256.f);
        }
        // loop-top BAR_FULL separates poolbuf reads from next im2col writes
    }
}

// ---------------------------------------------------------------------------
// k_mlp: one wave per sample. enc->f1->einsum->f2->concat->f3->f4->f5->out->softmax
// ---------------------------------------------------------------------------
__global__ __launch_bounds__(256, 4) void k_mlp(
    const float* __restrict__ pooled, const float* __restrict__ C,
    const float* __restrict__ ew, const float* __restrict__ eb,
    const float* __restrict__ w1, const float* __restrict__ b1,
    const float* __restrict__ w2, const float* __restrict__ b2,
    const float* __restrict__ w3, const float* __restrict__ b3,
    const float* __restrict__ w4, const float* __restrict__ b4,
    const float* __restrict__ w5, const float* __restrict__ b5,
    const float* __restrict__ ow, const float* __restrict__ ob,
    float* __restrict__ out)
{
    const int lane = threadIdx.x & 63;
    const int w    = threadIdx.x >> 6;
    const int b    = blockIdx.x * 4 + w;
    const int jc   = (lane < 50) ? lane : 0;   // clamp for 50-wide layers

    const float p0 = pooled[(size_t)b * 64 + lane];

    // enc: 64 -> 128, relu. lane holds j and j+64.
    float x1a = eb[lane], x1b = eb[lane + 64];
    #pragma unroll 8
    for (int i = 0; i < 64; ++i) {
        const float ai = rl(p0, i);
        x1a += ai * ew[i * 128 + lane];
        x1b += ai * ew[i * 128 + 64 + lane];
    }
    x1a = fmaxf(x1a, 0.f); x1b = fmaxf(x1b, 0.f);

    // f1: 128 -> 50, relu (lanes >= 50 compute garbage, never consumed)
    float x2 = b1[jc];
    #pragma unroll 8
    for (int i = 0; i < 64; ++i)  x2 += rl(x1a, i) * w1[i * 50 + jc];
    #pragma unroll 8
    for (int i = 0; i < 64; ++i)  x2 += rl(x1b, i) * w1[(64 + i) * 50 + jc];
    x2 = fmaxf(x2, 0.f);

    // einsum: e_i = sum_j C[b][i][j] * x2_j   (float2 reads: 25 instrs/lane)
    const float2* C2 = (const float2*)(C + (size_t)b * 2500 + jc * 50);
    float e = 0.f;
    #pragma unroll 5
    for (int j = 0; j < 25; ++j) {
        const float2 cc = C2[j];
        e += cc.x * rl(x2, 2 * j) + cc.y * rl(x2, 2 * j + 1);
    }

    // f2: 50 -> 128, relu
    float x3a = b2[lane], x3b = b2[lane + 64];
    #pragma unroll 10
    for (int i = 0; i < 50; ++i) {
        const float ai = rl(e, i);
        x3a += ai * w2[i * 128 + lane];
        x3b += ai * w2[i * 128 + 64 + lane];
    }
    x3a = fmaxf(x3a, 0.f); x3b = fmaxf(x3b, 0.f);

    // f3: concat(x1,x3) 256 -> 64, relu
    float x5 = b3[lane];
    #pragma unroll 8
    for (int i = 0; i < 64; ++i) x5 += rl(x1a, i) * w3[(i      ) * 64 + lane];
    #pragma unroll 8
    for (int i = 0; i < 64; ++i) x5 += rl(x1b, i) * w3[(64  + i) * 64 + lane];
    #pragma unroll 8
    for (int i = 0; i < 64; ++i) x5 += rl(x3a, i) * w3[(128 + i) * 64 + lane];
    #pragma unroll 8
    for (int i = 0; i < 64; ++i) x5 += rl(x3b, i) * w3[(192 + i) * 64 + lane];
    x5 = fmaxf(x5, 0.f);

    // f4, f5: 64 -> 64, relu
    float x6 = b4[lane];
    #pragma unroll 8
    for (int i = 0; i < 64; ++i) x6 += rl(x5, i) * w4[i * 64 + lane];
    x6 = fmaxf(x6, 0.f);
    float x7 = b5[lane];
    #pragma unroll 8
    for (int i = 0; i < 64; ++i) x7 += rl(x6, i) * w5[i * 64 + lane];
    x7 = fmaxf(x7, 0.f);

    // out: 64 -> 50, relu, softmax
    float lg = ob[jc];
    #pragma unroll 8
    for (int i = 0; i < 64; ++i) lg += rl(x7, i) * ow[i * 50 + jc];
    float z = (lane < 50) ? fmaxf(lg, 0.f) : -1e30f;

    float m = z;
    #pragma unroll
    for (int o = 32; o > 0; o >>= 1) m = fmaxf(m, __shfl_xor(m, o, 64));
    float pr = __expf(z - m);
    float sden = pr;
    #pragma unroll
    for (int o = 32; o > 0; o >>= 1) sden += __shfl_xor(sden, o, 64);

    if (lane < 50) out[(size_t)b * 50 + lane] = pr / sden;
}

// ---------------------------------------------------------------------------
extern "C" void kernel_launch(void* const* d_in, const int* in_sizes, int n_in,
                              void* d_out, int out_size, void* d_ws, size_t ws_size,
                              hipStream_t stream) {
    (void)in_sizes; (void)n_in; (void)out_size; (void)ws_size;
    const float* x   = (const float*)d_in[0];
    const float* Cm  = (const float*)d_in[1];
    const float* c1w = (const float*)d_in[2];
    const float* c1b = (const float*)d_in[3];
    const float* c2w = (const float*)d_in[4];
    const float* c2b = (const float*)d_in[5];
    const float* ew  = (const float*)d_in[6];
    const float* ebv = (const float*)d_in[7];
    const float* f1w = (const float*)d_in[8];
    const float* f1b = (const float*)d_in[9];
    const float* f2w = (const float*)d_in[10];
    const float* f2b = (const float*)d_in[11];
    const float* f3w = (const float*)d_in[12];
    const float* f3b = (const float*)d_in[13];
    const float* f4w = (const float*)d_in[14];
    const float* f4b = (const float*)d_in[15];
    const float* f5w = (const float*)d_in[16];
    const float* f5b = (const float*)d_in[17];
    const float* ow  = (const float*)d_in[18];
    const float* ob  = (const float*)d_in[19];

    short* packw  = (short*)d_ws;                      // 19456 shorts
    float* pooled = (float*)((char*)d_ws + 65536);     // 4096*64*4 B
    float* out    = (float*)d_out;

    hipLaunchKernelGGL(k_prep, dim3(76),   dim3(256), 0, stream, c2w, c1w, packw);
    hipLaunchKernelGGL(k_conv, dim3(256),  dim3(512), 0, stream, x, c1b, packw, c2b, pooled);
    hipLaunchKernelGGL(k_mlp,  dim3(1024), dim3(256), 0, stream, pooled, Cm,
                       ew, ebv, f1w, f1b, f2w, f2b, f3w, f3b, f4w, f4b, f5w, f5b,
                       ow, ob, out);
}

// Round 4
// 361.532 us; speedup vs baseline: 3.3736x; 1.0971x over previous
//
#include <hip/hip_runtime.h>
#include <hip/hip_bf16.h>

// ---------------------------------------------------------------------------
// Goal_Conditioned_Policies: conv(3->32,s2) relu, conv(32->64,s2) relu,
// mean-pool, MLP chain with per-sample einsum, softmax.
// B=4096, x[4096,3,64,64] fp32, C[4096,50,50] fp32, out [4096,50] fp32.
//
// Round 4: k_mlp rewritten as block-tile MFMA (16 samples/block, 256 blocks).
//   k_prep packs ALL weights: conv (as R3) + MLP weights transposed to bf16
//   [n][K+8] fragment layout (zero-padded) + padded fp32 biases.
//   k_mlp stages the 116 KB weight block to LDS once (29 exact
//   global_load_lds dwordx4 iters), then all layers via mfma 16x16x32 bf16
//   with activations ping-ponging through padded LDS buffers. einsum stays
//   VALU (compulsory 41 MB C stream). Softmax via width-16 shuffles.
//   k_conv unchanged from R3 (pooled moved to d_ws+163840).
// ---------------------------------------------------------------------------

typedef __attribute__((ext_vector_type(8)))  short short8;
typedef __attribute__((ext_vector_type(4)))  float floatx4;
typedef __attribute__((ext_vector_type(16))) float floatx16;

#define AS1 __attribute__((address_space(1)))
#define AS3 __attribute__((address_space(3)))

// barriers: lgkm-only keeps async global_load_lds (vmcnt) in flight
#define BAR_LGKM() asm volatile("s_waitcnt lgkmcnt(0)\ns_barrier" ::: "memory")
#define BAR_FULL() asm volatile("s_waitcnt vmcnt(0) lgkmcnt(0)\ns_barrier" ::: "memory")

__device__ __forceinline__ short f2bf(float f) {
    unsigned u = __float_as_uint(f);
    u += 0x7fffu + ((u >> 16) & 1u);   // round-to-nearest-even
    return (short)(u >> 16);
}

__device__ __forceinline__ unsigned pkbf2(float a, float b) {
    float2 fp; fp.x = a; fp.y = b;
    __hip_bfloat162 bb = __float22bfloat162_rn(fp);
    return *(unsigned*)&bb;
}

// ---------------------------------------------------------------------------
// d_ws layout (bytes):
//   0      : conv2 pack bf16 [pos][oc=64][ic=32]      36864
//   36864  : conv1 pack bf16 [oc=32][k=32]             2048
//   40960  : MLP block (staged verbatim to LDS)      118784 (=29*4096)
//            sh 0     ewT [128][72]   (K=64)
//            sh 9216  w1T [64][136]   (K=128, n>=50 zero)
//            sh 17920 w2T [128][72]   (K=50 pad 64, k>=50 zero)
//            sh 27136 w3T [64][264]   (K=256)
//            sh 44032 w4T [64][72]
//            sh 48640 w5T [64][72]
//            sh 53248 owT [64][72]    (n>=50 zero)
//            byte 115712: biases fp32 [576]: eb128|b1p64|b2 128|b3 64|b4 64|b5 64|obp64
//   163840 : pooled fp32 [4096][64]
// ---------------------------------------------------------------------------
#define WS_MLP_B    40960
#define WS_BIAS_B   (40960 + 115712)
#define WS_POOL_B   163840

__global__ void k_prep(const float* __restrict__ cw2, const float* __restrict__ cw1,
                       const float* __restrict__ ew,  const float* __restrict__ w1,
                       const float* __restrict__ w2,  const float* __restrict__ w3,
                       const float* __restrict__ w4,  const float* __restrict__ w5,
                       const float* __restrict__ ow,  const float* __restrict__ eb,
                       const float* __restrict__ b1,  const float* __restrict__ b2,
                       const float* __restrict__ b3,  const float* __restrict__ b4,
                       const float* __restrict__ b5,  const float* __restrict__ ob,
                       short* __restrict__ packw, float* __restrict__ biasout) {
    const int idx = blockIdx.x * 256 + threadIdx.x;
    if (idx < 18432) {                       // conv2: [pos][oc][ic]
        const int ic  = idx & 31;
        const int oc  = (idx >> 5) & 63;
        const int pos = idx >> 11;
        packw[idx] = f2bf(cw2[oc * 288 + ic * 9 + pos]);
    } else if (idx < 19456) {                // conv1: [oc][k=32]
        const int j  = idx - 18432;
        const int k  = j & 31;
        const int oc = j >> 5;
        packw[idx] = (k < 27) ? f2bf(cw1[oc * 27 + k]) : (short)0;
    } else if (idx < 77312) {                // MLP weights (transposed, padded)
        const int e = idx - 19456;
        short v;
        if (e < 9216)        { const int n = e / 72,  kk = e - n * 72;
            v = (kk < 64) ? f2bf(ew[kk * 128 + n]) : (short)0; }
        else if (e < 17920)  { const int r = e - 9216;  const int n = r / 136, kk = r - n * 136;
            v = (kk < 128 && n < 50) ? f2bf(w1[kk * 50 + n]) : (short)0; }
        else if (e < 27136)  { const int r = e - 17920; const int n = r / 72,  kk = r - n * 72;
            v = (kk < 50) ? f2bf(w2[kk * 128 + n]) : (short)0; }
        else if (e < 44032)  { const int r = e - 27136; const int n = r / 264, kk = r - n * 264;
            v = (kk < 256) ? f2bf(w3[kk * 64 + n]) : (short)0; }
        else if (e < 48640)  { const int r = e - 44032; const int n = r / 72,  kk = r - n * 72;
            v = (kk < 64) ? f2bf(w4[kk * 64 + n]) : (short)0; }
        else if (e < 53248)  { const int r = e - 48640; const int n = r / 72,  kk = r - n * 72;
            v = (kk < 64) ? f2bf(w5[kk * 64 + n]) : (short)0; }
        else                 { const int r = e - 53248; const int n = r / 72,  kk = r - n * 72;
            v = (kk < 64 && n < 50) ? f2bf(ow[kk * 50 + n]) : (short)0; }
        packw[20480 + e] = v;
    } else if (idx < 77888) {                // biases fp32, padded
        const int j = idx - 77312;
        float v;
        if (j < 128)      v = eb[j];
        else if (j < 192) v = (j - 128 < 50) ? b1[j - 128] : 0.f;
        else if (j < 320) v = b2[j - 192];
        else if (j < 384) v = b3[j - 320];
        else if (j < 448) v = b4[j - 384];
        else if (j < 512) v = b5[j - 448];
        else              v = (j - 512 < 50) ? ob[j - 512] : 0.f;
        biasout[j] = v;
    }
}

// ---------------------------------------------------------------------------
// k_conv (unchanged from R3): fused conv1(MFMA) + conv2(MFMA) + mean pool
// ---------------------------------------------------------------------------
#define XS_OFF  0
#define A1_OFF  49152
#define A1STR   80
#define H1_OFF  90112
#define ROWB    2064
#define SMEM_SZ (49152 + 40960 + 66048)
#define SPB     16

__global__ __launch_bounds__(512, 2) void k_conv(
    const float* __restrict__ x,    const float* __restrict__ c1b,
    const short* __restrict__ packw, const float* __restrict__ c2b,
    float* __restrict__ pooled)
{
    __shared__ __align__(16) char smem[SMEM_SZ];
    float* xs      = (float*)(smem + XS_OFF);
    char*  a1      = smem + A1_OFF;
    char*  h1b     = smem + H1_OFF;
    float* poolbuf = (float*)(smem + A1_OFF);

    const int tid  = threadIdx.x;
    const int lane = tid & 63;
    const int w    = tid >> 6;

    const int col = lane & 31;
    const int ss  = lane >> 5;

    const int nt  = w & 1;
    const int ox2 = lane & 15;
    const int oyb = (lane >> 4) & 1;
    const int ocn = nt * 32 + col;
    const float bias2 = c2b[ocn];

    short8 z8;
    #pragma unroll
    for (int i = 0; i < 8; ++i) z8[i] = 0;

    short8 bfr[9][2];
    #pragma unroll
    for (int pos = 0; pos < 9; ++pos)
        #pragma unroll
        for (int h = 0; h < 2; ++h)
            bfr[pos][h] = *(const short8*)(packw + (pos * 64 + ocn) * 32 + h * 16 + ss * 8);

    const short* w1p = packw + 18432;
    short8 w1f[2];
    #pragma unroll
    for (int k = 0; k < 2; ++k)
        w1f[k] = *(const short8*)(w1p + col * 32 + k * 16 + ss * 8);

    float2 b1p[8];
    #pragma unroll
    for (int rp = 0; rp < 8; ++rp)
        b1p[rp] = *(const float2*)(c1b + ((rp & 1) * 2 + (rp >> 1) * 8 + 4 * ss));

    int  sbv[3][2];
    bool okx[3];
    #pragma unroll
    for (int kx = 0; kx < 3; ++kx) {
        const int ph   = (kx + 1) & 1;
        const int xh   = ox2 - (kx == 0 ? 1 : 0);
        const int slot = ph * 16 + xh;
        const int swz  = (slot >> 1) & 3;
        okx[kx] = (xh >= 0);
        #pragma unroll
        for (int h = 0; h < 2; ++h)
            sbv[kx][h] = slot * 64 + (((ss + 2 * h) ^ swz) << 4);
    }

    const int slotpx = ((col & 1) << 4) + (col >> 1);
    const int wswz   = (slotpx >> 1) & 3;
    const int wbase  = slotpx * 64 + ss * 8;

    auto prefetch_x = [&](int bb) {
        const char* g = (const char*)(x + (size_t)bb * 12288);
        #pragma unroll
        for (int i = 0; i < 6; ++i) {
            const int off = (w * 6 + i) << 10;
            __builtin_amdgcn_global_load_lds(
                (const AS1 unsigned int*)(g + off + lane * 16),
                (AS3 unsigned int*)(smem + XS_OFF + off), 16, 0, 0);
        }
    };

    auto im2col = [&](int half) {
        const int p  = tid;
        const int oy = half * 16 + (p >> 5);
        const int ox = p & 31;
        float f[32];
        #pragma unroll
        for (int ic = 0; ic < 3; ++ic) {
            #pragma unroll
            for (int ky = 0; ky < 3; ++ky) {
                const int  iy   = 2 * oy + ky - 1;
                const bool oky  = iy >= 0;
                const int  base = ic * 4096 + (oky ? iy : 0) * 64 + 2 * ox;
                const float2 p12 = *(const float2*)(xs + base);
                const float2 pm  = *(const float2*)(xs + (base >= 2 ? base - 2 : 0));
                const int k = ic * 9 + ky * 3;
                f[k + 0] = (oky && ox > 0) ? pm.y : 0.f;
                f[k + 1] = oky ? p12.x : 0.f;
                f[k + 2] = oky ? p12.y : 0.f;
            }
        }
        f[27] = 0.f; f[28] = 0.f; f[29] = 0.f; f[30] = 0.f; f[31] = 0.f;
        unsigned pk[16];
        #pragma unroll
        for (int t = 0; t < 16; ++t) pk[t] = pkbf2(f[2 * t], f[2 * t + 1]);
        uint4* dst = (uint4*)(a1 + p * A1STR);
        dst[0] = make_uint4(pk[0],  pk[1],  pk[2],  pk[3]);
        dst[1] = make_uint4(pk[4],  pk[5],  pk[6],  pk[7]);
        dst[2] = make_uint4(pk[8],  pk[9],  pk[10], pk[11]);
        dst[3] = make_uint4(pk[12], pk[13], pk[14], pk[15]);
    };

    auto conv1_mfma = [&](int half) {
        #pragma unroll
        for (int i = 0; i < 2; ++i) {
            const int t = w * 2 + i;
            const char* abase = a1 + (t * 32 + col) * A1STR + ss * 16;
            const short8 bf0 = *(const short8*)(abase);
            const short8 bf1 = *(const short8*)(abase + 32);
            floatx16 acc;
            #pragma unroll
            for (int r = 0; r < 16; ++r) acc[r] = 0.f;
            acc = __builtin_amdgcn_mfma_f32_32x32x16_bf16(w1f[0], bf0, acc, 0, 0, 0);
            acc = __builtin_amdgcn_mfma_f32_32x32x16_bf16(w1f[1], bf1, acc, 0, 0, 0);
            const int oyg = half * 16 + t;
            char* hb = h1b + oyg * ROWB + wbase;
            #pragma unroll
            for (int rp = 0; rp < 8; ++rp) {
                const unsigned u = pkbf2(fmaxf(acc[2 * rp]     + b1p[rp].x, 0.f),
                                         fmaxf(acc[2 * rp + 1] + b1p[rp].y, 0.f));
                const int off = (((rp >> 1) ^ wswz) << 4) + (rp & 1) * 4;
                *(unsigned*)(hb + off) = u;
            }
        }
    };

    prefetch_x(blockIdx.x);

    #pragma unroll 1
    for (int s = 0; s < SPB; ++s) {
        const int b = blockIdx.x + (s << 8);

        BAR_FULL();
        im2col(0);
        BAR_LGKM();
        conv1_mfma(0);
        BAR_LGKM();
        im2col(1);
        BAR_LGKM();
        if (s + 1 < SPB) prefetch_x(blockIdx.x + ((s + 1) << 8));
        conv1_mfma(1);
        BAR_LGKM();

        const int t0 = w >> 1;
        float pool = 0.f;
        floatx16 acc0, acc1;
        #pragma unroll
        for (int r = 0; r < 16; ++r) { acc0[r] = 0.f; acc1[r] = 0.f; }
        #pragma unroll
        for (int ky = 0; ky < 3; ++ky) {
            #pragma unroll
            for (int kx = 0; kx < 3; ++kx) {
                const int  iy0 = t0 * 4 + oyb * 2 + ky - 1;
                const bool ok0 = okx[kx] && (iy0 >= 0);
                const bool ok1 = okx[kx];
                const int  ba0 = iy0 * ROWB;
                const int  ba1 = ba0 + 16 * ROWB;
                #pragma unroll
                for (int h = 0; h < 2; ++h) {
                    const int so = sbv[kx][h];
                    short8 a0v = ok0 ? *(const short8*)(h1b + ba0 + so) : z8;
                    short8 a1v = ok1 ? *(const short8*)(h1b + ba1 + so) : z8;
                    const short8 bf = bfr[ky * 3 + kx][h];
                    acc0 = __builtin_amdgcn_mfma_f32_32x32x16_bf16(a0v, bf, acc0, 0, 0, 0);
                    acc1 = __builtin_amdgcn_mfma_f32_32x32x16_bf16(a1v, bf, acc1, 0, 0, 0);
                }
            }
        }
        #pragma unroll
        for (int r = 0; r < 16; ++r) {
            pool += fmaxf(acc0[r] + bias2, 0.f);
            pool += fmaxf(acc1[r] + bias2, 0.f);
        }
        pool += __shfl_xor(pool, 32, 64);
        if (lane < 32) poolbuf[w * 32 + lane] = pool;
        BAR_LGKM();
        if (tid < 64) {
            const int g = tid >> 5, c = tid & 31;
            pooled[(size_t)b * 64 + tid] =
                (poolbuf[(g    ) * 32 + c] + poolbuf[(g + 2) * 32 + c] +
                 poolbuf[(g + 4) * 32 + c] + poolbuf[(g + 6) * 32 + c]) * (1.f / 256.f);
        }
    }
}

// ---------------------------------------------------------------------------
// k_mlp: 256 blocks x 16 samples, all shared-weight layers via MFMA 16x16x32.
// LDS map (bytes):
//   0      MLP weight+bias block staged verbatim from d_ws   118784
//   118784 P  pooled bf16 [16][72]                              2304
//   121088 A  act bf16 [16][264]  (x1 @0..127, x3 @128..255)    8448
//   129536 B  act bf16 [16][264]  (x2@0, e@64, x5@0, x6@64, x7@128) 8448
//   137984 Z  logits fp32 [16][68]                              4352
//   total 142336
// ---------------------------------------------------------------------------
#define ML_BIAS_B 115712
#define ML_P_SH   59392
#define ML_A_SH   60544
#define ML_B_SH   64768
#define ML_Z_F    34496
#define ML_SMEM   142336

__global__ __launch_bounds__(256, 1) void k_mlp(
    const char* __restrict__ wsblk,   // d_ws + WS_MLP_B (staged verbatim)
    const float* __restrict__ pooled, const float* __restrict__ C,
    float* __restrict__ out)
{
    __shared__ __align__(16) char smem[ML_SMEM];
    short*       Sw   = (short*)smem;
    const short* S    = (const short*)smem;
    const float* Bias = (const float*)(smem + ML_BIAS_B);
    float*       Zf   = (float*)smem;     // indexed from ML_Z_F

    const int tid    = threadIdx.x;
    const int lane   = tid & 63;
    const int w      = tid >> 6;
    const int n16    = lane & 15;
    const int q      = lane >> 4;
    const int tile16 = blockIdx.x * 16;

    // ---- stage weights+biases: 29 * 4096 B, exact, via global_load_lds ----
    #pragma unroll
    for (int i = 0; i < 29; ++i) {
        const int off = i * 4096 + w * 1024;
        __builtin_amdgcn_global_load_lds(
            (const AS1 unsigned int*)(wsblk + off + lane * 16),
            (AS3 unsigned int*)(smem + off), 16, 0, 0);
    }
    // ---- stage pooled tile -> P bf16 [16][72] ----
    {
        const float4 pv = *(const float4*)(pooled + tile16 * 64 + tid * 4);
        const int s = tid >> 4, k = (tid & 15) * 4;
        uint2 u;
        u.x = pkbf2(pv.x, pv.y);
        u.y = pkbf2(pv.z, pv.w);
        *(uint2*)(Sw + ML_P_SH + s * 72 + k) = u;
    }
    BAR_FULL();   // weights + pooled visible

    // ---- generic MFMA layer ----
    // in: act LDS [m=16][pitch] bf16 at inOff; weights [n][K+8] at wOff;
    // out: relu(acc+bias) -> bf16 act at outOff (pitch 264), or fp32 Z.
    auto layer = [&](int inOff, int inPitch, int K, int wOff, int nTiles,
                     int biasOff, int outOff, bool isOut) {
        #pragma unroll
        for (int nt = w; nt < nTiles; nt += 4) {
            floatx4 acc;
            acc[0] = 0.f; acc[1] = 0.f; acc[2] = 0.f; acc[3] = 0.f;
            const int kp = K + 8;
            #pragma unroll
            for (int kc = 0; kc < 8; ++kc) {        // K/32 chunks (max 8)
                if (kc * 32 >= K) break;
                const short8 aF = *(const short8*)(S + inOff + n16 * inPitch + kc * 32 + q * 8);
                const short8 bF = *(const short8*)(S + wOff + (nt * 16 + n16) * kp + kc * 32 + q * 8);
                acc = __builtin_amdgcn_mfma_f32_16x16x32_bf16(aF, bF, acc, 0, 0, 0);
            }
            const int   n  = nt * 16 + n16;
            const float bv = Bias[biasOff + n];
            #pragma unroll
            for (int r = 0; r < 4; ++r) {
                const int   m = q * 4 + r;
                const float v = fmaxf(acc[r] + bv, 0.f);
                if (isOut) Zf[ML_Z_F + m * 68 + n] = (n < 50) ? v : -1e30f;
                else       Sw[outOff + m * 264 + n] = f2bf(v);
            }
        }
    };

    layer(ML_P_SH, 72, 64, 0, 8, 0, ML_A_SH, false);            // enc -> x1 (A 0..127)
    BAR_LGKM();
    layer(ML_A_SH, 264, 128, 9216, 4, 128, ML_B_SH, false);     // f1 -> x2 (B 0..63)
    BAR_LGKM();

    // ---- einsum: e[s][i] = sum_j C[b][i][j] * x2[s][j], 800 items ----
    #pragma unroll
    for (int r = 0; r < 4; ++r) {
        const int item = tid + r * 256;
        if (item < 800) {
            const int s = (item * 1311) >> 16;      // item/50, exact for <800
            const int i = item - s * 50;
            const float* Cp = C + (size_t)(tile16 + s) * 2500 + i * 50;
            float e = 0.f;
            #pragma unroll
            for (int j2 = 0; j2 < 25; ++j2) {
                const float2   cc = *(const float2*)(Cp + 2 * j2);
                const unsigned u  = *(const unsigned*)(S + ML_B_SH + s * 264 + 2 * j2);
                e += cc.x * __uint_as_float(u << 16)
                   + cc.y * __uint_as_float(u & 0xffff0000u);
            }
            Sw[ML_B_SH + s * 264 + 64 + i] = f2bf(e);
        }
    }
    if ((tid & 15) < 14)                              // zero-pad e[50..63]
        Sw[ML_B_SH + (tid >> 4) * 264 + 64 + 50 + (tid & 15)] = 0;
    BAR_LGKM();

    layer(ML_B_SH + 64, 264, 64, 17920, 8, 192, ML_A_SH + 128, false); // f2 -> x3 (A 128..255)
    BAR_LGKM();
    layer(ML_A_SH, 264, 256, 27136, 4, 320, ML_B_SH, false);    // f3 (concat) -> x5 (B 0..63)
    BAR_LGKM();
    layer(ML_B_SH, 264, 64, 44032, 4, 384, ML_B_SH + 64, false);// f4 -> x6 (B 64..127)
    BAR_LGKM();
    layer(ML_B_SH + 64, 264, 64, 48640, 4, 448, ML_B_SH + 128, false); // f5 -> x7
    BAR_LGKM();
    layer(ML_B_SH + 128, 264, 64, 53248, 4, 512, 0, true);      // out -> Z (fp32)
    BAR_LGKM();

    // ---- softmax: 16 threads per sample, 4 logits each, width-16 shuffles ----
    {
        const int s = tid >> 4, g = tid & 15;
        const float4 zv = *(const float4*)(Zf + ML_Z_F + s * 68 + g * 4);
        float m = fmaxf(fmaxf(zv.x, zv.y), fmaxf(zv.z, zv.w));
        #pragma unroll
        for (int o = 8; o > 0; o >>= 1) m = fmaxf(m, __shfl_xor(m, o, 16));
        float4 p;
        p.x = __expf(zv.x - m); p.y = __expf(zv.y - m);
        p.z = __expf(zv.z - m); p.w = __expf(zv.w - m);
        float sum = p.x + p.y + p.z + p.w;
        #pragma unroll
        for (int o = 8; o > 0; o >>= 1) sum += __shfl_xor(sum, o, 16);
        const float inv = 1.f / sum;
        float* po = out + (size_t)(tile16 + s) * 50 + g * 4;
        const int j = g * 4;
        if (j     < 50) po[0] = p.x * inv;
        if (j + 1 < 50) po[1] = p.y * inv;
        if (j + 2 < 50) po[2] = p.z * inv;
        if (j + 3 < 50) po[3] = p.w * inv;
    }
}

// ---------------------------------------------------------------------------
extern "C" void kernel_launch(void* const* d_in, const int* in_sizes, int n_in,
                              void* d_out, int out_size, void* d_ws, size_t ws_size,
                              hipStream_t stream) {
    (void)in_sizes; (void)n_in; (void)out_size; (void)ws_size;
    const float* x   = (const float*)d_in[0];
    const float* Cm  = (const float*)d_in[1];
    const float* c1w = (const float*)d_in[2];
    const float* c1b = (const float*)d_in[3];
    const float* c2w = (const float*)d_in[4];
    const float* c2b = (const float*)d_in[5];
    const float* ew  = (const float*)d_in[6];
    const float* ebv = (const float*)d_in[7];
    const float* f1w = (const float*)d_in[8];
    const float* f1b = (const float*)d_in[9];
    const float* f2w = (const float*)d_in[10];
    const float* f2b = (const float*)d_in[11];
    const float* f3w = (const float*)d_in[12];
    const float* f3b = (const float*)d_in[13];
    const float* f4w = (const float*)d_in[14];
    const float* f4b = (const float*)d_in[15];
    const float* f5w = (const float*)d_in[16];
    const float* f5b = (const float*)d_in[17];
    const float* ow  = (const float*)d_in[18];
    const float* ob  = (const float*)d_in[19];

    short* packw   = (short*)d_ws;
    float* biasout = (float*)((char*)d_ws + WS_BIAS_B);
    float* pooled  = (float*)((char*)d_ws + WS_POOL_B);
    const char* wsblk = (const char*)d_ws + WS_MLP_B;
    float* out     = (float*)d_out;

    hipLaunchKernelGGL(k_prep, dim3(305), dim3(256), 0, stream,
                       c2w, c1w, ew, f1w, f2w, f3w, f4w, f5w, ow,
                       ebv, f1b, f2b, f3b, f4b, f5b, ob, packw, biasout);
    hipLaunchKernelGGL(k_conv, dim3(256), dim3(512), 0, stream,
                       x, c1b, packw, c2b, pooled);
    hipLaunchKernelGGL(k_mlp,  dim3(256), dim3(256), 0, stream,
                       wsblk, pooled, Cm, out);
}